// Round 4
// baseline (185.294 us; speedup 1.0000x reference)
//
#include <hip/hip_runtime.h>
#include <hip/hip_bf16.h>

#define D_DIM   128
#define MT      64        // node rows per block-iteration
#define NBLOCKS 512       // persistent: 2 blocks/CU x 256 CUs

typedef __attribute__((ext_vector_type(8))) short bf16x8;
typedef __attribute__((ext_vector_type(4))) float f32x4;

__device__ __forceinline__ unsigned short f2bf(float f) {
    return __builtin_bit_cast(unsigned short, __float2bfloat16(f));
}

// XOR-swizzled offset (in shorts) into a [rows][128] bf16 LDS tile.
// 16B chunks permuted per row: conflict-free ds_read_b128 with zero padding.
__device__ __forceinline__ int sw_off(int row, int col) {
    return row * 128 + ((((col >> 3) ^ (row & 15)) << 3) | (col & 7));
}

// stage a 128x128 fp32 matrix into swizzled bf16 LDS; coalesced global reads
__device__ __forceinline__ void stage_w(const float* __restrict__ w,
                                        unsigned short* __restrict__ sW, int t) {
    #pragma unroll
    for (int i = 0; i < 8; ++i) {                 // 4096 float4 / 512 threads
        const int idx4 = i * 512 + t;
        const float4 v = ((const float4*)w)[idx4];
        const int row = idx4 >> 5;                // 32 float4 per row
        const int c4  = (idx4 & 31) * 4;
        ushort4 b;
        b.x = f2bf(v.x); b.y = f2bf(v.y); b.z = f2bf(v.z); b.w = f2bf(v.w);
        *(ushort4*)&sW[sw_off(row, c4)] = b;      // 8B, 4-short aligned
    }
}

__global__ __launch_bounds__(512, 4)
void ctx_encoder(const int* __restrict__ nodes,
                 const float* __restrict__ c2e,
                 const float* __restrict__ w1,
                 const float* __restrict__ b1,
                 const float* __restrict__ w2,
                 const float* __restrict__ b2,
                 float* __restrict__ out,
                 int N) {
    __shared__ unsigned short sW1[D_DIM * 128];   // 32 KB
    __shared__ unsigned short sW2[D_DIM * 128];   // 32 KB
    __shared__ unsigned short sH [MT   * 128];    // 16 KB  -> 80 KB total, 2 blocks/CU

    const int t    = threadIdx.x;
    const int lane = t & 63;
    const int wave = t >> 6;       // 0..7
    const int pair = wave >> 1;    // m-tile 0..3 (16 rows each)
    const int half = wave & 1;     // ct-group: half*4 .. half*4+3
    const int cl   = lane & 15;
    const int quad = lane >> 4;

    // ---- stage both weight matrices once (persistent), hoist biases ----
    stage_w(w1, sW1, t);
    stage_w(w2, sW2, t);

    float bias1[4], bias2[4];
    #pragma unroll
    for (int c = 0; c < 4; ++c) {
        const int j = (half * 4 + c) * 16 + cl;
        bias1[c] = b1[j];
        bias2[c] = b2[j];
    }

    const int nTiles = (N + MT - 1) / MT;
    const int myrow  = pair * 16 + cl;            // my A-row within a tile
    int tl = blockIdx.x;

    // ---- prefetch pipeline: idx one iter ahead of gather, gather one phase ahead ----
    int r0 = tl * MT + myrow;            r0 = r0 < N ? r0 : N - 1;
    int idx_cur = nodes[r0];
    int idx_nxt = 0;
    if (tl + NBLOCKS < nTiles) {
        int r1 = (tl + NBLOCKS) * MT + myrow;  r1 = r1 < N ? r1 : N - 1;
        idx_nxt = nodes[r1];
    }

    float4 g[8];
    {
        const float* rowp = c2e + (size_t)idx_cur * D_DIM + quad * 8;
        #pragma unroll
        for (int ks = 0; ks < 4; ++ks) {
            g[2 * ks]     = *(const float4*)(rowp + ks * 32);
            g[2 * ks + 1] = *(const float4*)(rowp + ks * 32 + 4);
        }
    }
    __syncthreads();   // sW1/sW2 ready

    while (tl < nTiles) {
        // consume current gather into bf16 A-fragments
        bf16x8 aF[4];
        #pragma unroll
        for (int ks = 0; ks < 4; ++ks) {
            bf16x8 a;
            a[0] = (short)f2bf(g[2 * ks].x);     a[1] = (short)f2bf(g[2 * ks].y);
            a[2] = (short)f2bf(g[2 * ks].z);     a[3] = (short)f2bf(g[2 * ks].w);
            a[4] = (short)f2bf(g[2 * ks + 1].x); a[5] = (short)f2bf(g[2 * ks + 1].y);
            a[6] = (short)f2bf(g[2 * ks + 1].z); a[7] = (short)f2bf(g[2 * ks + 1].w);
            aF[ks] = a;
        }

        // issue next tile's gather now — hides under both MFMA phases
        const int tn = tl + NBLOCKS;
        if (tn < nTiles) {
            const float* rowp = c2e + (size_t)idx_nxt * D_DIM + quad * 8;
            #pragma unroll
            for (int ks = 0; ks < 4; ++ks) {
                g[2 * ks]     = *(const float4*)(rowp + ks * 32);
                g[2 * ks + 1] = *(const float4*)(rowp + ks * 32 + 4);
            }
            if (tn + NBLOCKS < nTiles) {
                int rn = (tn + NBLOCKS) * MT + myrow;  rn = rn < N ? rn : N - 1;
                idx_nxt = nodes[rn];
            }
        }

        // ---- layer 1: h = relu(ce @ W1^T + b1) -> sH ----
        #pragma unroll
        for (int c = 0; c < 4; ++c) {
            const int ct = half * 4 + c;
            bf16x8 bF[4];
            #pragma unroll
            for (int ks = 0; ks < 4; ++ks)
                bF[ks] = *(const bf16x8*)&sW1[sw_off(ct * 16 + cl, ks * 32 + quad * 8)];
            f32x4 acc = {0.f, 0.f, 0.f, 0.f};
            #pragma unroll
            for (int ks = 0; ks < 4; ++ks)
                acc = __builtin_amdgcn_mfma_f32_16x16x32_bf16(aF[ks], bF[ks], acc, 0, 0, 0);
            const int j = ct * 16 + cl;
            #pragma unroll
            for (int r = 0; r < 4; ++r) {
                float h = acc[r] + bias1[c];
                h = h > 0.f ? h : 0.f;
                sH[sw_off(pair * 16 + quad * 4 + r, j)] = f2bf(h);
            }
        }
        __syncthreads();

        // ---- layer 2: out = relu(h @ W2^T + b2) ----
        bf16x8 hF[4];
        #pragma unroll
        for (int ks = 0; ks < 4; ++ks)
            hF[ks] = *(const bf16x8*)&sH[sw_off(pair * 16 + cl, ks * 32 + quad * 8)];

        const size_t obase = (size_t)tl * MT;
        #pragma unroll
        for (int c = 0; c < 4; ++c) {
            const int ct = half * 4 + c;
            bf16x8 bF[4];
            #pragma unroll
            for (int ks = 0; ks < 4; ++ks)
                bF[ks] = *(const bf16x8*)&sW2[sw_off(ct * 16 + cl, ks * 32 + quad * 8)];
            f32x4 acc = {0.f, 0.f, 0.f, 0.f};
            #pragma unroll
            for (int ks = 0; ks < 4; ++ks)
                acc = __builtin_amdgcn_mfma_f32_16x16x32_bf16(hF[ks], bF[ks], acc, 0, 0, 0);
            const int j = ct * 16 + cl;
            #pragma unroll
            for (int r = 0; r < 4; ++r) {
                float o = acc[r] + bias2[c];
                o = o > 0.f ? o : 0.f;
                const long grow = (long)(obase + pair * 16 + quad * 4 + r);
                if (grow < N)
                    out[(size_t)grow * D_DIM + j] = o;
            }
        }
        __syncthreads();   // sH safe to overwrite next iteration

        tl += NBLOCKS;
    }
}

extern "C" void kernel_launch(void* const* d_in, const int* in_sizes, int n_in,
                              void* d_out, int out_size, void* d_ws, size_t ws_size,
                              hipStream_t stream) {
    const int*   nodes = (const int*)d_in[0];
    const float* c2e   = (const float*)d_in[1];
    const float* w1    = (const float*)d_in[2];
    const float* b1    = (const float*)d_in[3];
    const float* w2    = (const float*)d_in[4];
    const float* b2    = (const float*)d_in[5];
    float* out = (float*)d_out;
    const int N = in_sizes[0];

    ctx_encoder<<<dim3(NBLOCKS), dim3(512), 0, stream>>>(nodes, c2e, w1, b1, w2, b2, out, N);
}

// Round 5
// 164.939 us; speedup vs baseline: 1.1234x; 1.1234x over previous
//
#include <hip/hip_runtime.h>
#include <hip/hip_bf16.h>

#define D_DIM   128
#define MT      64        // node rows per block-iteration (3125 tiles exactly)
#define NBLOCKS 512       // persistent: 2 blocks/CU x 256 CUs
#define NTHR    512

typedef __attribute__((ext_vector_type(8))) short bf16x8;
typedef __attribute__((ext_vector_type(4))) float f32x4;

__device__ __forceinline__ unsigned short f2bf(float f) {
    return __builtin_bit_cast(unsigned short, __float2bfloat16(f));
}

// XOR-swizzled offset (in shorts) into a [rows][128] bf16 LDS tile.
// 16B chunks permuted per row: conflict-free ds_read_b128, zero padding.
__device__ __forceinline__ int sw_off(int row, int col) {
    return row * 128 + ((((col >> 3) ^ (row & 15)) << 3) | (col & 7));
}

// stage a 128x128 fp32 matrix into swizzled bf16 LDS; coalesced global reads
__device__ __forceinline__ void stage_w(const float* __restrict__ w,
                                        unsigned short* __restrict__ sW, int t) {
    #pragma unroll
    for (int i = 0; i < 8; ++i) {                 // 4096 float4 / 512 threads
        const int idx4 = i * NTHR + t;
        const float4 v = ((const float4*)w)[idx4];
        const int row = idx4 >> 5;                // 32 float4 per row
        const int c4  = (idx4 & 31) * 4;
        ushort4 b;
        b.x = f2bf(v.x); b.y = f2bf(v.y); b.z = f2bf(v.z); b.w = f2bf(v.w);
        *(ushort4*)&sW[sw_off(row, c4)] = b;
    }
}

__global__ __launch_bounds__(NTHR, 2)
void ctx_encoder(const int* __restrict__ nodes,
                 const float* __restrict__ c2e,
                 const float* __restrict__ w1,
                 const float* __restrict__ b1,
                 const float* __restrict__ w2,
                 const float* __restrict__ b2,
                 float* __restrict__ out,
                 int N) {
    __shared__ unsigned short sW1[D_DIM * 128];   // 32 KB
    __shared__ unsigned short sW2[D_DIM * 128];   // 32 KB
    __shared__ unsigned short sX [MT    * 128];   // 16 KB shared A/h buffer -> 80 KB

    const int t    = threadIdx.x;
    const int lane = t & 63;
    const int wave = t >> 6;       // 0..7
    const int pair = wave >> 1;    // m-tile 0..3 (16 rows)
    const int half = wave & 1;     // ct-group
    const int cl   = lane & 15;
    const int quad = lane >> 4;

    // gather role: thread t fetches 64B-contiguous-per-load slices of row grow0
    const int grow0 = t >> 3;      // row within tile, 0..63
    const int gc    = t & 7;       // 16B chunk position (8 lanes cover 128B runs)

    stage_w(w1, sW1, t);
    stage_w(w2, sW2, t);

    float bias1[4], bias2[4];
    #pragma unroll
    for (int c = 0; c < 4; ++c) {
        const int j = (half * 4 + c) * 16 + cl;
        bias1[c] = b1[j];
        bias2[c] = b2[j];
    }

    const int nTiles = (N + MT - 1) / MT;
    int tl = blockIdx.x;

    // ---- prologue: gather tile0, prefetch next idx ----
    int r0 = tl * MT + grow0;  r0 = r0 < N ? r0 : N - 1;
    int idx_cur = nodes[r0];
    float4 g[4];
    {
        const float* rp = c2e + (size_t)idx_cur * D_DIM + gc * 4;
        #pragma unroll
        for (int i = 0; i < 4; ++i)
            g[i] = *(const float4*)(rp + i * 32);   // per-instr: 8x128B contiguous runs
    }
    int idx_nxt = 0;
    if (tl + NBLOCKS < nTiles) {
        int r1 = (tl + NBLOCKS) * MT + grow0;  r1 = r1 < N ? r1 : N - 1;
        idx_nxt = nodes[r1];
    }
    __syncthreads();   // weights staged

    while (tl < nTiles) {
        // ---- s1: gathered rows -> bf16 -> sX (swizzled) ----
        #pragma unroll
        for (int i = 0; i < 4; ++i) {
            ushort4 b;
            b.x = f2bf(g[i].x); b.y = f2bf(g[i].y);
            b.z = f2bf(g[i].z); b.w = f2bf(g[i].w);
            *(ushort4*)&sX[sw_off(grow0, gc * 4 + i * 32)] = b;
        }
        __syncthreads();   // B1: sX(A) ready

        // ---- s2: A-fragments from LDS ----
        bf16x8 aF[4];
        #pragma unroll
        for (int ks = 0; ks < 4; ++ks)
            aF[ks] = *(const bf16x8*)&sX[sw_off(pair * 16 + cl, ks * 32 + quad * 8)];

        // ---- s3: issue next tile's gather (hides under both MFMA phases) ----
        const int tn = tl + NBLOCKS;
        if (tn < nTiles) {
            const float* rp = c2e + (size_t)idx_nxt * D_DIM + gc * 4;
            #pragma unroll
            for (int i = 0; i < 4; ++i)
                g[i] = *(const float4*)(rp + i * 32);
            if (tn + NBLOCKS < nTiles) {
                int rn = (tn + NBLOCKS) * MT + grow0;  rn = rn < N ? rn : N - 1;
                idx_nxt = nodes[rn];
            }
        }
        __syncthreads();   // B2: all aF reads done; sX reusable for h

        // ---- s4: layer 1 -> h into sX ----
        #pragma unroll
        for (int c = 0; c < 4; ++c) {
            const int ct = half * 4 + c;
            bf16x8 bF[4];
            #pragma unroll
            for (int ks = 0; ks < 4; ++ks)
                bF[ks] = *(const bf16x8*)&sW1[sw_off(ct * 16 + cl, ks * 32 + quad * 8)];
            f32x4 acc = {0.f, 0.f, 0.f, 0.f};
            #pragma unroll
            for (int ks = 0; ks < 4; ++ks)
                acc = __builtin_amdgcn_mfma_f32_16x16x32_bf16(aF[ks], bF[ks], acc, 0, 0, 0);
            const int j = ct * 16 + cl;
            #pragma unroll
            for (int r = 0; r < 4; ++r) {
                float h = acc[r] + bias1[c];
                h = h > 0.f ? h : 0.f;
                sX[sw_off(pair * 16 + quad * 4 + r, j)] = f2bf(h);
            }
        }
        __syncthreads();   // B3: sX(h) ready

        // ---- s5: h-fragments ----
        bf16x8 hF[4];
        #pragma unroll
        for (int ks = 0; ks < 4; ++ks)
            hF[ks] = *(const bf16x8*)&sX[sw_off(pair * 16 + cl, ks * 32 + quad * 8)];
        __syncthreads();   // B4: hF reads done; sX free for next iter's gather

        // ---- s6: layer 2 + store ----
        const size_t obase = (size_t)tl * MT;
        #pragma unroll
        for (int c = 0; c < 4; ++c) {
            const int ct = half * 4 + c;
            bf16x8 bF[4];
            #pragma unroll
            for (int ks = 0; ks < 4; ++ks)
                bF[ks] = *(const bf16x8*)&sW2[sw_off(ct * 16 + cl, ks * 32 + quad * 8)];
            f32x4 acc = {0.f, 0.f, 0.f, 0.f};
            #pragma unroll
            for (int ks = 0; ks < 4; ++ks)
                acc = __builtin_amdgcn_mfma_f32_16x16x32_bf16(hF[ks], bF[ks], acc, 0, 0, 0);
            const int j = ct * 16 + cl;
            #pragma unroll
            for (int r = 0; r < 4; ++r) {
                float o = acc[r] + bias2[c];
                o = o > 0.f ? o : 0.f;
                const long grow = (long)(obase + pair * 16 + quad * 4 + r);
                if (grow < N)
                    out[(size_t)grow * D_DIM + j] = o;
            }
        }

        tl += NBLOCKS;
    }
}

extern "C" void kernel_launch(void* const* d_in, const int* in_sizes, int n_in,
                              void* d_out, int out_size, void* d_ws, size_t ws_size,
                              hipStream_t stream) {
    const int*   nodes = (const int*)d_in[0];
    const float* c2e   = (const float*)d_in[1];
    const float* w1    = (const float*)d_in[2];
    const float* b1    = (const float*)d_in[3];
    const float* w2    = (const float*)d_in[4];
    const float* b2    = (const float*)d_in[5];
    float* out = (float*)d_out;
    const int N = in_sizes[0];

    ctx_encoder<<<dim3(NBLOCKS), dim3(NTHR), 0, stream>>>(nodes, c2e, w1, b1, w2, b2, out, N);
}